// Round 3
// baseline (539.107 us; speedup 1.0000x reference)
//
#include <hip/hip_runtime.h>
#include <math.h>

// Workspace float offsets
#define OFF_BF 0         // Bf[2 p][128 w][16 y']   : cosT(w*(2y'+p)), no weight
#define OFF_AF 4096      // Af[128 h][64 r]         : cosT(k1(r)*h), no weight
#define OFF_CF 12288     // Cf[64 r][128 h]         : wr(r)*cosT(k1(r)*h)
#define OFF_DF 20480     // Df[2 yp][16 y'][128 w]  : wy(y)*cosT(y*w)
#define OFF_Y  24576     // Y [512 bi][64 r][2 yp][16 y']
#define OFF_Z  1073152   // Z [512 bo][64 r][32 y]

#define F4E(v,k) ((k)==0?(v).x:(k)==1?(v).y:(k)==2?(v).z:(v).w)

__device__ __forceinline__ float cosT(int p) {
    // cos(pi * p / 255), exact integer argument reduction to [0, pi]
    int r = p % 510;
    if (r > 255) r = 510 - r;
    return cosf((float)r * (3.14159265358979323846f / 255.0f));
}

__global__ __launch_bounds__(256) void init_basis(float* __restrict__ ws) {
    int idx = blockIdx.x * 256 + threadIdx.x;
    if (idx < 4096) {                        // Bf[p][w][y'] = cosT(w*(2y'+p))
        int p = idx >> 11, w = (idx >> 4) & 127, yq = idx & 15;
        ws[OFF_BF + idx] = cosT(w * (2 * yq + p));
    } else if (idx < 12288) {                // Af[h][r] = cosT(k1*h)
        int j = idx - 4096; int h = j >> 6, r = j & 63;
        int k1 = (r < 32) ? r : r + 192;
        ws[OFF_AF + j] = cosT(k1 * h);
    } else if (idx < 20480) {                // Cf[r][h] = wr*cosT(k1*h)
        int j = idx - 12288; int r = j >> 7, h = j & 127;
        int k1 = (r < 32) ? r : r + 192;
        float wr = (r == 0 || r == 63) ? 1.f : 2.f;
        ws[OFF_CF + j] = wr * cosT(k1 * h);
    } else if (idx < 24576) {                // Df[yp][y'][w] = wy*cosT(y*w)
        int j = idx - 20480; int yp = j >> 11, yq = (j >> 7) & 15, w = j & 127;
        int y = 2 * yq + yp;
        float wy = (y == 0) ? 1.f : 2.f;
        ws[OFF_DF + j] = wy * cosT(y * w);
    }
}

// ---------------- forward projection: Y[bi][r][yp][y'] ----------------
// 128 threads, grid 512 (2 blocks/CU). Symmetry-folded K=128 both stages.
// LDS 32KB: S[2 p][256][8] @0, Bf copy @4096; U[2 rp][2 yp][128][16] @0 (overlaps
// dead S+Bf after last GEMM read).
__global__ __launch_bounds__(128, 1) void fwd_kernel(const float* __restrict__ x,
                                                     const float* __restrict__ ws,
                                                     float* __restrict__ Y) {
    __shared__ float lds[8192];
    const int t = threadIdx.x;
    const int bi = blockIdx.x;
    const float* xp = x + (size_t)bi * 65536;

    // load Bf table into LDS (4096 floats @4096)
#pragma unroll
    for (int k = 0; k < 8; ++k) {
        int i4 = k * 512 + t * 4;
        *(float4*)&lds[4096 + i4] = *(const float4*)(ws + OFF_BF + i4);
    }

    // staging ids: thread covers rows {r4+64m}, f4-slot sj within the 8-float chunk row
    const int sj = t & 1;
    const int sj4 = 4 * sj;
    const int r4 = t >> 1;

    // compute ids: wave = y-parity p; yh picks 8 of 16 y'; hb picks the row quads
    const int hb = t & 31;
    const int yh = (t >> 5) & 1;
    const int p  = t >> 6;         // wave-uniform
    const int yb = yh * 8;

    const int rows[8] = {hb, 127 - hb, 128 + hb, 255 - hb,
                         hb + 32, 95 - hb, 160 + hb, 223 - hb};

    float4 f0, f1, f2, f3, g0, g1, g2, g3;

#define FWD_LOAD(cc) { \
    int fb = 8 * (cc) + sj4, rb = 252 - 8 * (cc) - sj4; \
    f0 = *(const float4*)(xp + (r4      ) * 256 + fb); \
    f1 = *(const float4*)(xp + (r4 + 64 ) * 256 + fb); \
    f2 = *(const float4*)(xp + (r4 + 128) * 256 + fb); \
    f3 = *(const float4*)(xp + (r4 + 192) * 256 + fb); \
    g0 = *(const float4*)(xp + (r4      ) * 256 + rb); \
    g1 = *(const float4*)(xp + (r4 + 64 ) * 256 + rb); \
    g2 = *(const float4*)(xp + (r4 + 128) * 256 + rb); \
    g3 = *(const float4*)(xp + (r4 + 192) * 256 + rb); }

#define FWD_STORE1(cc, FF, GG, M) { \
    int rw = r4 + 64 * (M); \
    int ps = rw * 8 + ((sj ^ ((rw >> 2) & 1)) << 2); \
    float wA = ((cc) == 0 && sj == 0) ? 1.f : 2.f; \
    float4 sp, sm; \
    sp.x = wA  * (FF.x + GG.w); sm.x = wA  * (FF.x - GG.w); \
    sp.y = 2.f * (FF.y + GG.z); sm.y = 2.f * (FF.y - GG.z); \
    sp.z = 2.f * (FF.z + GG.y); sm.z = 2.f * (FF.z - GG.y); \
    sp.w = 2.f * (FF.w + GG.x); sm.w = 2.f * (FF.w - GG.x); \
    *(float4*)&lds[ps] = sp; *(float4*)&lds[2048 + ps] = sm; }

#define FWD_STORE(cc) { FWD_STORE1(cc, f0, g0, 0); FWD_STORE1(cc, f1, g1, 1); \
                        FWD_STORE1(cc, f2, g2, 2); FWD_STORE1(cc, f3, g3, 3); }

    float acc[8][8];
#pragma unroll
    for (int m = 0; m < 8; ++m)
#pragma unroll
        for (int yy = 0; yy < 8; ++yy) acc[m][yy] = 0.f;

    FWD_LOAD(0);
    FWD_STORE(0);
    __syncthreads();

    for (int c = 0; c < 16; ++c) {
        if (c < 15) FWD_LOAD(c + 1);
        // GEMM on chunk c: T1-partial[rows][y'] += S_p[row][w]*Bf[p][w][y']
#pragma unroll
        for (int jj = 0; jj < 2; ++jj) {
            float4 sv[8];
#pragma unroll
            for (int m = 0; m < 8; ++m) {
                int rw = rows[m];
                sv[m] = *(float4*)&lds[p * 2048 + rw * 8 + ((jj ^ ((rw >> 2) & 1)) << 2)];
            }
#pragma unroll
            for (int k = 0; k < 4; ++k) {
                int wi = 8 * c + 4 * jj + k;
                float4 b0 = *(float4*)&lds[4096 + p * 2048 + wi * 16 + yb];
                float4 b1 = *(float4*)&lds[4096 + p * 2048 + wi * 16 + yb + 4];
                float bv[8] = {b0.x, b0.y, b0.z, b0.w, b1.x, b1.y, b1.z, b1.w};
#pragma unroll
                for (int m = 0; m < 8; ++m) {
                    float s = F4E(sv[m], k);
#pragma unroll
                    for (int yy = 0; yy < 8; ++yy) acc[m][yy] += s * bv[yy];
                }
            }
        }
        __syncthreads();
        if (c < 15) {
            FWD_STORE(c + 1);
            __syncthreads();
        }
    }

    // fold T1 -> U (h-symmetry, weights wh) and write to LDS @0 (S/Bf dead now)
    {
        const int s0 = 2 * yh, s1 = 2 * yh + 1;
#define UWRITE(H, WGT, A, B) { \
        int key = ((H) >> 1) & 3; \
        float* up = &lds[p * 2048 + (H) * 16]; \
        float* um = up + 4096; \
        int p0 = (s0 ^ key) << 2, p1 = (s1 ^ key) << 2; \
        *(float4*)&up[p0] = make_float4(WGT*(acc[A][0]+acc[B][0]), WGT*(acc[A][1]+acc[B][1]), \
                                        WGT*(acc[A][2]+acc[B][2]), WGT*(acc[A][3]+acc[B][3])); \
        *(float4*)&up[p1] = make_float4(WGT*(acc[A][4]+acc[B][4]), WGT*(acc[A][5]+acc[B][5]), \
                                        WGT*(acc[A][6]+acc[B][6]), WGT*(acc[A][7]+acc[B][7])); \
        *(float4*)&um[p0] = make_float4(WGT*(acc[A][0]-acc[B][0]), WGT*(acc[A][1]-acc[B][1]), \
                                        WGT*(acc[A][2]-acc[B][2]), WGT*(acc[A][3]-acc[B][3])); \
        *(float4*)&um[p1] = make_float4(WGT*(acc[A][4]-acc[B][4]), WGT*(acc[A][5]-acc[B][5]), \
                                        WGT*(acc[A][6]-acc[B][6]), WGT*(acc[A][7]-acc[B][7])); }
        float wq = (hb == 0) ? 1.f : 2.f;
        UWRITE(hb,       wq,  0, 3);
        UWRITE(127 - hb, 2.f, 1, 2);
        UWRITE(hb + 32,  2.f, 4, 7);
        UWRITE(95 - hb,  2.f, 5, 6);
    }
    __syncthreads();

    // stage 2 (folded): Y[r][y] = sum_{h<128} Af[h][r] * U_{r&1}[y&1][h][y>>1]
    {
        const int par = t >> 6;            // wave-uniform r-parity
        const int l = t & 63;
        const int ys2 = l & 3;
        const int idx4 = l >> 2;
        const int rA = par + 4 * idx4, rB = rA + 2;
        const float* Af = ws + OFF_AF;
        float a2[2][2][4];
#pragma unroll
        for (int i = 0; i < 2; ++i)
#pragma unroll
            for (int j = 0; j < 2; ++j)
#pragma unroll
                for (int k = 0; k < 4; ++k) a2[i][j][k] = 0.f;
#pragma unroll 4
        for (int h = 0; h < 128; ++h) {
            int sl = (ys2 ^ ((h >> 1) & 3)) << 2;
            float4 u0 = *(float4*)&lds[par * 4096 + h * 16 + sl];
            float4 u1 = *(float4*)&lds[par * 4096 + 2048 + h * 16 + sl];
            float af0 = Af[h * 64 + rA];
            float af1 = Af[h * 64 + rB];
#pragma unroll
            for (int k = 0; k < 4; ++k) {
                float e0 = F4E(u0, k), e1 = F4E(u1, k);
                a2[0][0][k] += af0 * e0; a2[0][1][k] += af0 * e1;
                a2[1][0][k] += af1 * e0; a2[1][1][k] += af1 * e1;
            }
        }
        float* Yp = Y + (size_t)bi * 2048;
        *(float4*)(Yp + rA * 32      + 4 * ys2) = make_float4(a2[0][0][0], a2[0][0][1], a2[0][0][2], a2[0][0][3]);
        *(float4*)(Yp + rA * 32 + 16 + 4 * ys2) = make_float4(a2[0][1][0], a2[0][1][1], a2[0][1][2], a2[0][1][3]);
        *(float4*)(Yp + rB * 32      + 4 * ys2) = make_float4(a2[1][0][0], a2[1][0][1], a2[1][0][2], a2[1][0][3]);
        *(float4*)(Yp + rB * 32 + 16 + 4 * ys2) = make_float4(a2[1][1][0], a2[1][1][1], a2[1][1][2], a2[1][1][3]);
    }
}

// ---------------- per-mode channel mixing: Z[b,o,r,y] ----------------
__global__ __launch_bounds__(256) void mix_kernel(const float* __restrict__ w1,
                                                  const float* __restrict__ w2,
                                                  const float* __restrict__ Yv,
                                                  float* __restrict__ Z) {
    const int r  = blockIdx.x & 63;
    const int og = blockIdx.x >> 6;
    const int t  = threadIdx.x;
    const int ys = t & 15;                  // y' index; y = 2*ys
    const int o  = og * 4 + ((t >> 4) & 3);
    const int bp = t >> 6;

    const float* Wb = ((r < 32) ? (w1 + r * 32) : (w2 + (r - 32) * 32)) + o * 1024 + 2 * ys;
    const float* Y0 = Yv + (size_t)(bp * 64) * 2048 + r * 32 + ys;   // [yp=0][ys]
    const float* Y1 = Y0 + (size_t)4 * 64 * 2048;

    float a00 = 0.f, a01 = 0.f, a10 = 0.f, a11 = 0.f;
#pragma unroll 4
    for (int i = 0; i < 64; ++i) {
        float2 wv = *(const float2*)(Wb + (size_t)i * 65536);
        float pe = Y0[i * 2048], po = Y0[i * 2048 + 16];
        float qe = Y1[i * 2048], qo = Y1[i * 2048 + 16];
        a00 += pe * wv.x; a01 += po * wv.y;
        a10 += qe * wv.x; a11 += qo * wv.y;
    }
    float2 r0; r0.x = a00; r0.y = a01;
    float2 r1; r1.x = a10; r1.y = a11;
    *(float2*)(Z + (size_t)(bp * 64 + o) * 2048 + r * 32 + 2 * ys) = r0;
    *(float2*)(Z + (size_t)((bp + 4) * 64 + o) * 2048 + r * 32 + 2 * ys) = r1;
}

// ---------------- inverse projection: out[b,o,h,w] ----------------
// 256 threads, grid 512 (2 blocks/CU). Folded both stages (K=32+32, K=16+16).
// LDS 56KB: Zs[2][64][16] @0, T2s[2 yp][256][16] @2048, Df copy @10240.
__global__ __launch_bounds__(256, 2) void inv_kernel(const float* __restrict__ ws,
                                                     const float* __restrict__ Zv,
                                                     float* __restrict__ out) {
    __shared__ float lds[14336];
    const int t = threadIdx.x;
    const float* Zp = Zv + (size_t)blockIdx.x * 2048;
    float* op = out + (size_t)blockIdx.x * 65536;

    // stage Df (4096 floats)
#pragma unroll
    for (int k = 0; k < 4; ++k) {
        int i4 = k * 1024 + t * 4;
        *(float4*)&lds[10240 + i4] = *(const float4*)(ws + OFF_DF + i4);
    }
    // stage Z parity-split: Zs[p][r][y']
    {
        int base = t * 8;
        int r = base >> 5;
        int q = (base & 31) >> 1;
        float4 v0 = *(const float4*)(Zp + base);
        float4 v1 = *(const float4*)(Zp + base + 4);
        float* z0 = &lds[r * 16];
        float* z1 = &lds[1024 + r * 16];
        z0[q]     = v0.x; z1[q]     = v0.y; z0[q + 1] = v0.z; z1[q + 1] = v0.w;
        z0[q + 2] = v1.x; z1[q + 2] = v1.y; z0[q + 3] = v1.z; z1[q + 3] = v1.w;
    }
    __syncthreads();

    // stage A: E/O partial sums, fold to T2 rows {hb, hb+64, 255-hb, 191-hb}
    {
        const int hb = t & 63;
        const int q4 = t >> 6;          // wave-uniform
        const int zp = q4 & 1;          // y-parity
        const int yh = q4 >> 1;
        const int yb = yh * 8;
        float aE0[8], aE1[8], aO0[8], aO1[8];
#pragma unroll
        for (int k = 0; k < 8; ++k) { aE0[k] = aE1[k] = aO0[k] = aO1[k] = 0.f; }
        const float* Cfp = ws + OFF_CF + hb;
#pragma unroll 2
        for (int rr = 0; rr < 32; ++rr) {
            int re = 2 * rr, ro = 2 * rr + 1;
            float c0 = Cfp[re * 128], c1 = Cfp[re * 128 + 64];
            float4 z0 = *(float4*)&lds[zp * 1024 + re * 16 + yb];
            float4 z1 = *(float4*)&lds[zp * 1024 + re * 16 + yb + 4];
            float zv[8] = {z0.x, z0.y, z0.z, z0.w, z1.x, z1.y, z1.z, z1.w};
#pragma unroll
            for (int k = 0; k < 8; ++k) { aE0[k] += c0 * zv[k]; aE1[k] += c1 * zv[k]; }
            float c2 = Cfp[ro * 128], c3 = Cfp[ro * 128 + 64];
            float4 z2 = *(float4*)&lds[zp * 1024 + ro * 16 + yb];
            float4 z3 = *(float4*)&lds[zp * 1024 + ro * 16 + yb + 4];
            float zw[8] = {z2.x, z2.y, z2.z, z2.w, z3.x, z3.y, z3.z, z3.w};
#pragma unroll
            for (int k = 0; k < 8; ++k) { aO0[k] += c2 * zw[k]; aO1[k] += c3 * zw[k]; }
        }
        const int s0 = 2 * yh, s1 = 2 * yh + 1;
#define T2WRITE(H, A, B, SGN) { \
        int key = ((H) >> 1) & 3; \
        float* tp = &lds[2048 + zp * 4096 + (H) * 16]; \
        *(float4*)&tp[(s0 ^ key) << 2] = make_float4(A[0] SGN B[0], A[1] SGN B[1], A[2] SGN B[2], A[3] SGN B[3]); \
        *(float4*)&tp[(s1 ^ key) << 2] = make_float4(A[4] SGN B[4], A[5] SGN B[5], A[6] SGN B[6], A[7] SGN B[7]); }
        T2WRITE(hb,       aE0, aO0, +);
        T2WRITE(hb + 64,  aE1, aO1, +);
        T2WRITE(255 - hb, aE0, aO0, -);
        T2WRITE(191 - hb, aE1, aO1, -);
    }
    __syncthreads();

    // stage B: P/Q partial sums over y, fold to out cols (w, 255-w)
    {
        const int wg = t & 7;
        const int hg2 = (t >> 3) & 31;
        for (int hh = 0; hh < 2; ++hh) {
            const int h0 = hg2 + 128 * hh;      // rows h0 + 32j
            float P[4][4][4], Q[4][4][4];
#pragma unroll
            for (int j = 0; j < 4; ++j)
#pragma unroll
                for (int m = 0; m < 4; ++m)
#pragma unroll
                    for (int e = 0; e < 4; ++e) { P[j][m][e] = 0.f; Q[j][m][e] = 0.f; }
#pragma unroll
            for (int yp = 0; yp < 2; ++yp) {
#pragma unroll
                for (int yg = 0; yg < 4; ++yg) {
                    float4 tv[4];
#pragma unroll
                    for (int j = 0; j < 4; ++j) {
                        int hj = h0 + 32 * j;
                        tv[j] = *(float4*)&lds[2048 + yp * 4096 + hj * 16 + ((yg ^ ((hj >> 1) & 3)) << 2)];
                    }
#pragma unroll
                    for (int k = 0; k < 4; ++k) {
                        int yq = 4 * yg + k;
                        float4 dv[4];
#pragma unroll
                        for (int m = 0; m < 4; ++m)
                            dv[m] = *(float4*)&lds[10240 + yp * 2048 + yq * 128 + 4 * wg + 32 * m];
#pragma unroll
                        for (int j = 0; j < 4; ++j) {
                            float tvv = F4E(tv[j], k);
#pragma unroll
                            for (int m = 0; m < 4; ++m)
#pragma unroll
                                for (int e = 0; e < 4; ++e) {
                                    float pr = tvv * F4E(dv[m], e);
                                    if (yp == 0) P[j][m][e] += pr; else Q[j][m][e] += pr;
                                }
                        }
                    }
                }
            }
            // write out: fwd cols 4wg+32m, mirrored cols 252-4wg-32m (reversed)
#pragma unroll
            for (int j = 0; j < 4; ++j) {
                int h = h0 + 32 * j;
                float* orow = op + h * 256;
#pragma unroll
                for (int m = 0; m < 4; ++m) {
                    float4 fw, mv;
                    fw.x = P[j][m][0] + Q[j][m][0]; fw.y = P[j][m][1] + Q[j][m][1];
                    fw.z = P[j][m][2] + Q[j][m][2]; fw.w = P[j][m][3] + Q[j][m][3];
                    mv.x = P[j][m][3] - Q[j][m][3]; mv.y = P[j][m][2] - Q[j][m][2];
                    mv.z = P[j][m][1] - Q[j][m][1]; mv.w = P[j][m][0] - Q[j][m][0];
                    *(float4*)(orow + 4 * wg + 32 * m) = fw;
                    *(float4*)(orow + 252 - 4 * wg - 32 * m) = mv;
                }
            }
        }
    }
}

extern "C" void kernel_launch(void* const* d_in, const int* in_sizes, int n_in,
                              void* d_out, int out_size, void* d_ws, size_t ws_size,
                              hipStream_t stream) {
    const float* x  = (const float*)d_in[0];
    const float* w1 = (const float*)d_in[1];
    const float* w2 = (const float*)d_in[2];
    float* out = (float*)d_out;
    float* ws  = (float*)d_ws;   // needs ~8.5 MB

    hipLaunchKernelGGL(init_basis, dim3(96), dim3(256), 0, stream, ws);
    hipLaunchKernelGGL(fwd_kernel, dim3(512), dim3(128), 0, stream, x, ws, ws + OFF_Y);
    hipLaunchKernelGGL(mix_kernel, dim3(1024), dim3(256), 0, stream, w1, w2,
                       ws + OFF_Y, ws + OFF_Z);
    hipLaunchKernelGGL(inv_kernel, dim3(512), dim3(256), 0, stream, ws, ws + OFF_Z, out);
}

// Round 4
// 473.529 us; speedup vs baseline: 1.1385x; 1.1385x over previous
//
#include <hip/hip_runtime.h>
#include <math.h>

// Workspace float offsets
#define OFF_BF 0         // Bf[2 p][128 w][16 y']   : cosT(w*(2y'+p)), no weight
#define OFF_AF 4096      // Af[128 h][64 r]         : cosT(k1(r)*h), no weight
#define OFF_CF 12288     // Cf[64 r][128 h]         : wr(r)*cosT(k1(r)*h)
#define OFF_DF 20480     // Df[2 yp][16 y'][128 w]  : wy(y)*cosT(y*w)
#define OFF_Y  24576     // Y [512 bi][64 r][2 yp][16 y']
#define OFF_Z  1073152   // Z [512 bo][64 r][32 y]

#define F4E(v,k) ((k)==0?(v).x:(k)==1?(v).y:(k)==2?(v).z:(v).w)

__device__ __forceinline__ float cosT(int p) {
    // cos(pi * p / 255), exact integer argument reduction to [0, pi]
    int r = p % 510;
    if (r > 255) r = 510 - r;
    return cosf((float)r * (3.14159265358979323846f / 255.0f));
}

__global__ __launch_bounds__(256) void init_basis(float* __restrict__ ws) {
    int idx = blockIdx.x * 256 + threadIdx.x;
    if (idx < 4096) {                        // Bf[p][w][y'] = cosT(w*(2y'+p))
        int p = idx >> 11, w = (idx >> 4) & 127, yq = idx & 15;
        ws[OFF_BF + idx] = cosT(w * (2 * yq + p));
    } else if (idx < 12288) {                // Af[h][r] = cosT(k1*h)
        int j = idx - 4096; int h = j >> 6, r = j & 63;
        int k1 = (r < 32) ? r : r + 192;
        ws[OFF_AF + j] = cosT(k1 * h);
    } else if (idx < 20480) {                // Cf[r][h] = wr*cosT(k1*h)
        int j = idx - 12288; int r = j >> 7, h = j & 127;
        int k1 = (r < 32) ? r : r + 192;
        float wr = (r == 0 || r == 63) ? 1.f : 2.f;
        ws[OFF_CF + j] = wr * cosT(k1 * h);
    } else if (idx < 24576) {                // Df[yp][y'][w] = wy*cosT(y*w)
        int j = idx - 20480; int yp = j >> 11, yq = (j >> 7) & 15, w = j & 127;
        int y = 2 * yq + yp;
        float wy = (y == 0) ? 1.f : 2.f;
        ws[OFF_DF + j] = wy * cosT(y * w);
    }
}

// ---------------- forward projection: Y[bi][r][yp][y'] ----------------
// 256 threads, grid 512 (2 blocks/CU = 16 waves/CU). Folded K=128 both stages.
// LDS 48KB: S[2 p][256][16] @0 (8192f), Bf[2][128][16] @8192 (4096f).
// U[2 rp][2 yp][128][16] overlays S @0 after stage 1.
__global__ __launch_bounds__(256, 2) void fwd_kernel(const float* __restrict__ x,
                                                     const float* __restrict__ ws,
                                                     float* __restrict__ Y) {
    __shared__ float lds[12288];
    const int t = threadIdx.x;
    const int bi = blockIdx.x;
    const float* xp = x + (size_t)bi * 65536;

    // load Bf (4096 floats) @8192
#pragma unroll
    for (int k = 0; k < 4; ++k) {
        int i4 = k * 1024 + t * 4;
        *(float4*)&lds[8192 + i4] = *(const float4*)(ws + OFF_BF + i4);
    }

    // staging ids: 4 lanes per row (64-B segments), rows {r0 + 64m}
    const int q  = t & 3;
    const int r0 = t >> 2;                    // 0..63
    const int skey = (r0 >> 1) & 3;           // == ((r0+64m)>>1)&3 for all m
    const int soff = 4 * (q ^ skey);

    // compute ids: p = y-parity plane (wave-pair uniform), yh = y'-half, hb = row-fold id
    const int hb = t & 63;
    const int yh = (t >> 6) & 1;
    const int p  = t >> 7;
    const int yb = yh * 8;

    const int rows[4] = {hb, 127 - hb, 128 + hb, 255 - hb};
    int rkey[4];
#pragma unroll
    for (int m = 0; m < 4; ++m) rkey[m] = (rows[m] >> 1) & 3;

    float4 f[4], g[4];

#define FWD_LOAD(cc) { \
    int fb = 16 * (cc) + 4 * q, rb = 252 - 16 * (cc) - 4 * q; \
    _Pragma("unroll") \
    for (int m = 0; m < 4; ++m) { \
        f[m] = *(const float4*)(xp + (r0 + 64 * m) * 256 + fb); \
        g[m] = *(const float4*)(xp + (r0 + 64 * m) * 256 + rb); } }

#define FWD_STORE(cc) { \
    float wA = ((cc) == 0 && q == 0) ? 1.f : 2.f; \
    _Pragma("unroll") \
    for (int m = 0; m < 4; ++m) { \
        int ps = (r0 + 64 * m) * 16 + soff; \
        float4 sp, sm; \
        sp.x = wA  * (f[m].x + g[m].w); sm.x = wA  * (f[m].x - g[m].w); \
        sp.y = 2.f * (f[m].y + g[m].z); sm.y = 2.f * (f[m].y - g[m].z); \
        sp.z = 2.f * (f[m].z + g[m].y); sm.z = 2.f * (f[m].z - g[m].y); \
        sp.w = 2.f * (f[m].w + g[m].x); sm.w = 2.f * (f[m].w - g[m].x); \
        *(float4*)&lds[ps] = sp; *(float4*)&lds[4096 + ps] = sm; } }

    float acc[4][8];
#pragma unroll
    for (int m = 0; m < 4; ++m)
#pragma unroll
        for (int yy = 0; yy < 8; ++yy) acc[m][yy] = 0.f;

    FWD_LOAD(0);
    FWD_STORE(0);
    __syncthreads();

    for (int c = 0; c < 8; ++c) {
        if (c < 7) FWD_LOAD(c + 1);
        // GEMM chunk c: acc[m][yy] += S_p[rows[m]][w] * Bf[p][w][yb+yy], w in [16c,16c+16)
#pragma unroll
        for (int kk = 0; kk < 4; ++kk) {
            float4 sv[4];
#pragma unroll
            for (int m = 0; m < 4; ++m)
                sv[m] = *(float4*)&lds[p * 4096 + rows[m] * 16 + 4 * (kk ^ rkey[m])];
#pragma unroll
            for (int e = 0; e < 4; ++e) {
                int wi = 16 * c + 4 * kk + e;
                float4 b0 = *(float4*)&lds[8192 + p * 2048 + wi * 16 + yb];
                float4 b1 = *(float4*)&lds[8192 + p * 2048 + wi * 16 + yb + 4];
                float bv[8] = {b0.x, b0.y, b0.z, b0.w, b1.x, b1.y, b1.z, b1.w};
#pragma unroll
                for (int m = 0; m < 4; ++m) {
                    float s = F4E(sv[m], e);
#pragma unroll
                    for (int yy = 0; yy < 8; ++yy) acc[m][yy] += s * bv[yy];
                }
            }
        }
        __syncthreads();
        if (c < 7) {
            FWD_STORE(c + 1);
            __syncthreads();
        }
    }

    // fold T1 -> U (h-symmetry) into LDS @0 (S dead). U layout: [rp:+/-][p][128][16]
    {
        const int s0 = 2 * yh, s1 = 2 * yh + 1;
#define UWRITE(H, WGT, A, B) { \
        int key = ((H) >> 1) & 3; \
        float* up = &lds[p * 2048 + (H) * 16]; \
        float* um = up + 4096; \
        int p0 = (s0 ^ key) << 2, p1 = (s1 ^ key) << 2; \
        *(float4*)&up[p0] = make_float4(WGT*(acc[A][0]+acc[B][0]), WGT*(acc[A][1]+acc[B][1]), \
                                        WGT*(acc[A][2]+acc[B][2]), WGT*(acc[A][3]+acc[B][3])); \
        *(float4*)&up[p1] = make_float4(WGT*(acc[A][4]+acc[B][4]), WGT*(acc[A][5]+acc[B][5]), \
                                        WGT*(acc[A][6]+acc[B][6]), WGT*(acc[A][7]+acc[B][7])); \
        *(float4*)&um[p0] = make_float4(WGT*(acc[A][0]-acc[B][0]), WGT*(acc[A][1]-acc[B][1]), \
                                        WGT*(acc[A][2]-acc[B][2]), WGT*(acc[A][3]-acc[B][3])); \
        *(float4*)&um[p1] = make_float4(WGT*(acc[A][4]-acc[B][4]), WGT*(acc[A][5]-acc[B][5]), \
                                        WGT*(acc[A][6]-acc[B][6]), WGT*(acc[A][7]-acc[B][7])); }
        float wq = (hb == 0) ? 1.f : 2.f;
        UWRITE(hb,       wq,  0, 3);
        UWRITE(127 - hb, 2.f, 1, 2);
    }
    __syncthreads();

    // stage 2 (folded): Y[r][y] = sum_{h<128} Af[h][r] * U_{r&1}[y&1][h][y>>1]
    {
        const int par = (t >> 6) & 1;          // r parity (wave-uniform)
        const int quarter = t >> 7;            // wave-uniform
        const int l = t & 63;
        const int ys2 = l & 3;
        const int idx8 = l >> 2;               // 0..15
        const int r = par + 2 * quarter + 4 * idx8;
        const float* Af = ws + OFF_AF;
        float a2[2][4];
#pragma unroll
        for (int j = 0; j < 2; ++j)
#pragma unroll
            for (int k = 0; k < 4; ++k) a2[j][k] = 0.f;
#pragma unroll 4
        for (int h = 0; h < 128; ++h) {
            int sl = (ys2 ^ ((h >> 1) & 3)) << 2;
            float4 u0 = *(float4*)&lds[par * 4096 + h * 16 + sl];
            float4 u1 = *(float4*)&lds[par * 4096 + 2048 + h * 16 + sl];
            float af = Af[h * 64 + r];
#pragma unroll
            for (int k = 0; k < 4; ++k) {
                a2[0][k] += af * F4E(u0, k);
                a2[1][k] += af * F4E(u1, k);
            }
        }
        float* Yp = Y + (size_t)bi * 2048 + r * 32 + 4 * ys2;
        *(float4*)Yp        = make_float4(a2[0][0], a2[0][1], a2[0][2], a2[0][3]);
        *(float4*)(Yp + 16) = make_float4(a2[1][0], a2[1][1], a2[1][2], a2[1][3]);
    }
}

// ---------------- per-mode channel mixing: Z[b,o,r,y] ----------------
__global__ __launch_bounds__(256) void mix_kernel(const float* __restrict__ w1,
                                                  const float* __restrict__ w2,
                                                  const float* __restrict__ Yv,
                                                  float* __restrict__ Z) {
    const int r  = blockIdx.x & 63;
    const int og = blockIdx.x >> 6;
    const int t  = threadIdx.x;
    const int ys = t & 15;                  // y' index; y = 2*ys
    const int o  = og * 4 + ((t >> 4) & 3);
    const int bp = t >> 6;

    const float* Wb = ((r < 32) ? (w1 + r * 32) : (w2 + (r - 32) * 32)) + o * 1024 + 2 * ys;
    const float* Y0 = Yv + (size_t)(bp * 64) * 2048 + r * 32 + ys;   // [yp=0][ys]
    const float* Y1 = Y0 + (size_t)4 * 64 * 2048;

    float a00 = 0.f, a01 = 0.f, a10 = 0.f, a11 = 0.f;
#pragma unroll 4
    for (int i = 0; i < 64; ++i) {
        float2 wv = *(const float2*)(Wb + (size_t)i * 65536);
        float pe = Y0[i * 2048], po = Y0[i * 2048 + 16];
        float qe = Y1[i * 2048], qo = Y1[i * 2048 + 16];
        a00 += pe * wv.x; a01 += po * wv.y;
        a10 += qe * wv.x; a11 += qo * wv.y;
    }
    float2 r0; r0.x = a00; r0.y = a01;
    float2 r1; r1.x = a10; r1.y = a11;
    *(float2*)(Z + (size_t)(bp * 64 + o) * 2048 + r * 32 + 2 * ys) = r0;
    *(float2*)(Z + (size_t)((bp + 4) * 64 + o) * 2048 + r * 32 + 2 * ys) = r1;
}

// ---------------- inverse projection: out[b,o,h,w] ----------------
// grid 1024: block = (bo, hh) -> 4 blocks/CU = 16 waves/CU. Folded both stages.
// LDS 40KB: Zs[2 p][64 r][16 y'] @0 (2048f), T2h[2 yp][128 hloc][16 y'] @2048 (4096f),
// Df[2 yp][16 y'][128 w] @6144 (4096f). Stage-B: two m-half passes, 64 accs (no spill).
__global__ __launch_bounds__(256, 2) void inv_kernel(const float* __restrict__ ws,
                                                     const float* __restrict__ Zv,
                                                     float* __restrict__ out) {
    __shared__ float lds[10240];
    const int t = threadIdx.x;
    const int bo = blockIdx.x >> 1;
    const int hh = blockIdx.x & 1;
    const float* Zp = Zv + (size_t)bo * 2048;
    float* op = out + (size_t)bo * 65536 + hh * 32768;

    // stage Df (4096 floats)
#pragma unroll
    for (int k = 0; k < 4; ++k) {
        int i4 = k * 1024 + t * 4;
        *(float4*)&lds[6144 + i4] = *(const float4*)(ws + OFF_DF + i4);
    }
    // stage Z parity-split: Zs[p][r][y']
    {
        int base = t * 8;
        int r = base >> 5;
        int qq = (base & 31) >> 1;
        float4 v0 = *(const float4*)(Zp + base);
        float4 v1 = *(const float4*)(Zp + base + 4);
        float* z0 = &lds[r * 16];
        float* z1 = &lds[1024 + r * 16];
        z0[qq]     = v0.x; z1[qq]     = v0.y; z0[qq + 1] = v0.z; z1[qq + 1] = v0.w;
        z0[qq + 2] = v1.x; z1[qq + 2] = v1.y; z0[qq + 3] = v1.z; z1[qq + 3] = v1.w;
    }
    __syncthreads();

    // stage A: E/O partials over r; fold to this block's T2 half with sign (+ for hh=0)
    {
        const int hb = t & 63;
        const int q4 = t >> 6;          // wave-uniform
        const int zp = q4 & 1;          // y-parity
        const int yh = q4 >> 1;
        const int yb = yh * 8;
        float aE0[8], aE1[8], aO0[8], aO1[8];
#pragma unroll
        for (int k = 0; k < 8; ++k) { aE0[k] = aE1[k] = aO0[k] = aO1[k] = 0.f; }
        const float* Cfp = ws + OFF_CF + hb;
#pragma unroll 2
        for (int rr = 0; rr < 32; ++rr) {
            int re = 2 * rr, ro = 2 * rr + 1;
            float c0 = Cfp[re * 128], c1 = Cfp[re * 128 + 64];
            float4 z0 = *(float4*)&lds[zp * 1024 + re * 16 + yb];
            float4 z1 = *(float4*)&lds[zp * 1024 + re * 16 + yb + 4];
            float zv[8] = {z0.x, z0.y, z0.z, z0.w, z1.x, z1.y, z1.z, z1.w};
#pragma unroll
            for (int k = 0; k < 8; ++k) { aE0[k] += c0 * zv[k]; aE1[k] += c1 * zv[k]; }
            float c2 = Cfp[ro * 128], c3 = Cfp[ro * 128 + 64];
            float4 z2 = *(float4*)&lds[zp * 1024 + ro * 16 + yb];
            float4 z3 = *(float4*)&lds[zp * 1024 + ro * 16 + yb + 4];
            float zw[8] = {z2.x, z2.y, z2.z, z2.w, z3.x, z3.y, z3.z, z3.w};
#pragma unroll
            for (int k = 0; k < 8; ++k) { aO0[k] += c2 * zw[k]; aO1[k] += c3 * zw[k]; }
        }
        const int s0 = 2 * yh, s1 = 2 * yh + 1;
#define T2WRITE(H, A, B, SGN) { \
        int key = ((H) >> 1) & 3; \
        float* tp = &lds[2048 + zp * 2048 + (H) * 16]; \
        *(float4*)&tp[(s0 ^ key) << 2] = make_float4(A[0] SGN B[0], A[1] SGN B[1], A[2] SGN B[2], A[3] SGN B[3]); \
        *(float4*)&tp[(s1 ^ key) << 2] = make_float4(A[4] SGN B[4], A[5] SGN B[5], A[6] SGN B[6], A[7] SGN B[7]); }
        if (hh == 0) {
            T2WRITE(hb,      aE0, aO0, +);
            T2WRITE(hb + 64, aE1, aO1, +);
        } else {
            T2WRITE(127 - hb, aE0, aO0, -);   // global row 255-hb
            T2WRITE(63 - hb,  aE1, aO1, -);   // global row 191-hb
        }
    }
    __syncthreads();

    // stage B: out[h][w] = sum_y T2[h][y]*Df[y][w], w-mirror fold; two m-half passes
    {
        const int wg = t & 7;
        const int hg2 = (t >> 3) & 31;
        for (int mh = 0; mh < 2; ++mh) {
            float P[4][2][4], Q[4][2][4];
#pragma unroll
            for (int j = 0; j < 4; ++j)
#pragma unroll
                for (int mm = 0; mm < 2; ++mm)
#pragma unroll
                    for (int e = 0; e < 4; ++e) { P[j][mm][e] = 0.f; Q[j][mm][e] = 0.f; }
#pragma unroll
            for (int yp = 0; yp < 2; ++yp) {
#pragma unroll
                for (int yg = 0; yg < 4; ++yg) {
                    float4 tv[4];
#pragma unroll
                    for (int j = 0; j < 4; ++j) {
                        int hj = hg2 + 32 * j;
                        tv[j] = *(float4*)&lds[2048 + yp * 2048 + hj * 16 + ((yg ^ ((hj >> 1) & 3)) << 2)];
                    }
#pragma unroll
                    for (int k = 0; k < 4; ++k) {
                        int yq = 4 * yg + k;
                        float4 dv[2];
#pragma unroll
                        for (int mm = 0; mm < 2; ++mm)
                            dv[mm] = *(float4*)&lds[6144 + yp * 2048 + yq * 128 + 4 * wg + 32 * (2 * mh + mm)];
#pragma unroll
                        for (int j = 0; j < 4; ++j) {
                            float tvv = F4E(tv[j], k);
#pragma unroll
                            for (int mm = 0; mm < 2; ++mm)
#pragma unroll
                                for (int e = 0; e < 4; ++e) {
                                    float pr = tvv * F4E(dv[mm], e);
                                    if (yp == 0) P[j][mm][e] += pr; else Q[j][mm][e] += pr;
                                }
                        }
                    }
                }
            }
            // write: fwd cols 4wg+32m, mirrored cols 252-4wg-32m (elements reversed)
#pragma unroll
            for (int j = 0; j < 4; ++j) {
                float* orow = op + (hg2 + 32 * j) * 256;
#pragma unroll
                for (int mm = 0; mm < 2; ++mm) {
                    int m = 2 * mh + mm;
                    float4 fw, mv;
                    fw.x = P[j][mm][0] + Q[j][mm][0]; fw.y = P[j][mm][1] + Q[j][mm][1];
                    fw.z = P[j][mm][2] + Q[j][mm][2]; fw.w = P[j][mm][3] + Q[j][mm][3];
                    mv.x = P[j][mm][3] - Q[j][mm][3]; mv.y = P[j][mm][2] - Q[j][mm][2];
                    mv.z = P[j][mm][1] - Q[j][mm][1]; mv.w = P[j][mm][0] - Q[j][mm][0];
                    *(float4*)(orow + 4 * wg + 32 * m) = fw;
                    *(float4*)(orow + 252 - 4 * wg - 32 * m) = mv;
                }
            }
        }
    }
}

extern "C" void kernel_launch(void* const* d_in, const int* in_sizes, int n_in,
                              void* d_out, int out_size, void* d_ws, size_t ws_size,
                              hipStream_t stream) {
    const float* x  = (const float*)d_in[0];
    const float* w1 = (const float*)d_in[1];
    const float* w2 = (const float*)d_in[2];
    float* out = (float*)d_out;
    float* ws  = (float*)d_ws;   // needs ~8.5 MB

    hipLaunchKernelGGL(init_basis, dim3(96), dim3(256), 0, stream, ws);
    hipLaunchKernelGGL(fwd_kernel, dim3(512), dim3(256), 0, stream, x, ws, ws + OFF_Y);
    hipLaunchKernelGGL(mix_kernel, dim3(1024), dim3(256), 0, stream, w1, w2,
                       ws + OFF_Y, ws + OFF_Z);
    hipLaunchKernelGGL(inv_kernel, dim3(1024), dim3(256), 0, stream, ws, ws + OFF_Z, out);
}